// Round 10
// baseline (198.398 us; speedup 1.0000x reference)
//
#include <hip/hip_runtime.h>

// HashLoss: contrastive (logsumexp over ln@ln^T/0.2) + 0.5*MSE(H@H^T/128, Tn@Tn^T)
//         + 0.01*mean||logits|-1|
// B=4096. R10: distill term reformulated via trace identity:
//   Sum (hash_sim - teacher_sim)^2 = ||H^T H||^2/128^2 - 2||H^T Tn||^2/128 + ||Tn^T Tn||^2
// With Q=[H(+-1) | Tn*sqrt128] fp8 (R8-proven): dtot = Sum w_ij (Q^T Q)_ij^2,
// w=+1 within H/H and T/T blocks, -1 cross; same final scale as R9.
// C = Q^T Q: 7x7 triangle of 128x128 tiles (28) x split-K2 = 56 G-blocks
// (byte-gather LDS reads do the transpose). S-role (contrastive) unchanged.
// NO fences/release atomics in mega (R4/R8 lesson). 4 dispatches.

typedef __bf16 bf16x8 __attribute__((ext_vector_type(8)));
typedef float f32x4 __attribute__((ext_vector_type(4)));

__device__ __forceinline__ unsigned short f2bf(float f) {
  union { float f; unsigned int u; } v; v.f = f;
  unsigned int u = v.u;
  return (unsigned short)((u + 0x7FFFu + ((u >> 16) & 1u)) >> 16);  // RNE
}

// ---- prep: one wave per row, no LDS. 1024 blocks x 256 threads.
__global__ __launch_bounds__(256) void prep(const float* __restrict__ logits,
                                            const float* __restrict__ hash,
                                            const float* __restrict__ teacher,
                                            unsigned short* __restrict__ P,
                                            unsigned char* __restrict__ Q,
                                            float* __restrict__ qpart,
                                            float* __restrict__ rowexp,
                                            float* __restrict__ possum,
                                            float* __restrict__ cntw,
                                            float* __restrict__ dtot) {
  const int r = blockIdx.x * 4 + (threadIdx.x >> 6);
  const int lane = threadIdx.x & 63;
  float2 tv[6];
  float ss = 0.f;
#pragma unroll
  for (int i = 0; i < 6; ++i) {
    tv[i] = *(const float2*)&teacher[(size_t)r * 768 + i * 128 + 2 * lane];
    ss += tv[i].x * tv[i].x + tv[i].y * tv[i].y;
  }
  const float2 lv = *(const float2*)&logits[(size_t)r * 128 + 2 * lane];
  const float2 hv = *(const float2*)&hash[(size_t)r * 128 + 2 * lane];
  float ssl = lv.x * lv.x + lv.y * lv.y;
  float qv = fabsf(fabsf(lv.x) - 1.f) + fabsf(fabsf(lv.y) - 1.f);
#pragma unroll
  for (int off = 1; off < 64; off <<= 1) {
    ss += __shfl_xor(ss, off, 64);
    ssl += __shfl_xor(ssl, off, 64);
    qv += __shfl_xor(qv, off, 64);
  }
  // teacher scaled by sqrt(128)/||t||
  const float rnt = 11.313708498984761f / fmaxf(sqrtf(ss), 1e-12f);
  const float rnl = 1.f / fmaxf(sqrtf(ssl), 1e-12f);
  unsigned int pb = (unsigned int)f2bf(lv.x * rnl) |
                    ((unsigned int)f2bf(lv.y * rnl) << 16);
  *(unsigned int*)&P[(size_t)r * 128 + 2 * lane] = pb;
  // Q cols 0..127: hash as exact +-1.0 in e4m3 (0x38 / 0xB8)
  unsigned short hb = (unsigned short)((hv.x >= 0.f ? 0x38 : 0xB8) |
                                       ((hv.y >= 0.f ? 0x38 : 0xB8) << 8));
  *(unsigned short*)&Q[(size_t)r * 896 + 2 * lane] = hb;
#pragma unroll
  for (int i = 0; i < 6; ++i) {
    int p = __builtin_amdgcn_cvt_pk_fp8_f32(tv[i].x * rnt, tv[i].y * rnt, 0, false);
    *(unsigned short*)&Q[(size_t)r * 896 + 128 + i * 128 + 2 * lane] =
        (unsigned short)(p & 0xFFFF);
  }
  if (lane == 0) {
    qpart[r] = qv;
    rowexp[r] = 0.f; possum[r] = 0.f; cntw[r] = 0.f;
    if (r == 0) *dtot = 0.f;
  }
}

// Stage 128 rows x 128 BYTES from gA (and gB if offdiag) into LDS bytes
// [0..16K) / [16K..32K). LDS 16B-slot p of row holds global chunk p^(row&7).
#define STAGE_GEN(GA, GB, PITCH)                                               \
  {                                                                            \
    _Pragma("unroll") for (int it = 0; it < 4; ++it) {                         \
      const int task = it * 256 + t;                                           \
      const int row = task >> 3;                                               \
      const int c16 = (task & 7) ^ (row & 7);                                  \
      const unsigned char* gpA = (GA) + (size_t)row * (PITCH) + c16 * 16;      \
      __builtin_amdgcn_global_load_lds(                                        \
          (const __attribute__((address_space(1))) void*)gpA,                  \
          (__attribute__((address_space(3))) void*)&SB[it * 4096 + wave * 1024],\
          16, 0, 0);                                                           \
      if (offdiag) {                                                           \
        const unsigned char* gpB = (GB) + (size_t)row * (PITCH) + c16 * 16;    \
        __builtin_amdgcn_global_load_lds(                                      \
            (const __attribute__((address_space(1))) void*)gpB,                \
            (__attribute__((address_space(3)))                                 \
                 void*)&SB[16384 + it * 4096 + wave * 1024],                   \
            16, 0, 0);                                                         \
      }                                                                        \
    }                                                                          \
  }

// bf16 chunk (64 cols = 2 ksteps), 16 MFMA each. Wave (wy,wx) owns 64x64 quad.
#define MFMA_B()                                                               \
  {                                                                            \
    _Pragma("unroll") for (int ks = 0; ks < 2; ++ks) {                         \
      const int ph = ((ks * 4 + qd) ^ (l15 & 7)) * 16;                         \
      bf16x8 af[4], bfr[4];                                                    \
      _Pragma("unroll") for (int rt = 0; rt < 4; ++rt)                         \
          af[rt] = *(const bf16x8*)&SB[(wy * 64 + rt * 16 + l15) * 128 + ph];  \
      _Pragma("unroll") for (int ct = 0; ct < 4; ++ct)                         \
          bfr[ct] = *(const bf16x8*)&SB[boffB +                                \
                                        (wx * 64 + ct * 16 + l15) * 128 + ph]; \
      _Pragma("unroll") for (int rt = 0; rt < 4; ++rt)                         \
          _Pragma("unroll") for (int ct = 0; ct < 4; ++ct) acc[rt][ct] =       \
          __builtin_amdgcn_mfma_f32_16x16x32_bf16(af[rt], bfr[ct],             \
                                                  acc[rt][ct], 0, 0, 0);       \
    }                                                                          \
  }

__global__ __launch_bounds__(256, 3) void mega(const unsigned short* __restrict__ P,
                                               const unsigned char* __restrict__ Q,
                                               const void* __restrict__ mask,
                                               float* __restrict__ rowexp,
                                               float* __restrict__ possum,
                                               float* __restrict__ cntw,
                                               float* __restrict__ Cpart) {
  __shared__ __align__(16) unsigned char SB[32768];  // A @0, B @16384
  __shared__ float redrow[128][2], redcol[128][2];

  const int t = threadIdx.x;
  const int wave = t >> 6, lane = t & 63;
  const int qd = lane >> 4, l15 = lane & 15;
  const int wy = wave >> 1, wx = wave & 1;
  const int b = (int)blockIdx.x;

  f32x4 acc[4][4];
#pragma unroll
  for (int rt = 0; rt < 4; ++rt)
#pragma unroll
    for (int ct = 0; ct < 4; ++ct) acc[rt][ct] = {0.f, 0.f, 0.f, 0.f};

  if (b < 56) {
    // ---- G-role: C = Q^T Q tile (I,J), split-K half s. K-slab = 2048 rows.
    const int tile = b >> 1, s = b & 1;
    int I = 0, rem = tile;
    while (rem >= 7 - I) { rem -= 7 - I; ++I; }
    const int J = I + rem;
    const bool offdiag = (I != J);
    const int boffB = offdiag ? 16384 : 0;
    const unsigned char* QA = Q + (size_t)s * 2048 * 896 + I * 128;
    const unsigned char* QB = Q + (size_t)s * 2048 * 896 + J * 128;

    for (int cc = 0; cc < 16; ++cc) {
      __syncthreads();
      STAGE_GEN(QA + (size_t)cc * 114688, QB + (size_t)cc * 114688, 896);
      __syncthreads();
      // transpose-on-read: A[m=l15][k=qd*8+j] = Qslab[k][I*128 + colbyte]
#pragma unroll
      for (int ks = 0; ks < 4; ++ks) {
        const int ksr = ks * 32 + qd * 8;
        unsigned long af[4], bfr[4];
#pragma unroll
        for (int rt = 0; rt < 4; ++rt) {
          const int cA = wy * 4 + rt;
          unsigned long v = 0;
#pragma unroll
          for (int j = 0; j < 8; ++j)
            v |= (unsigned long)SB[(ksr + j) * 128 + ((cA ^ j) << 4) + l15]
                 << (8 * j);
          af[rt] = v;
        }
#pragma unroll
        for (int ct = 0; ct < 4; ++ct) {
          const int cB = wx * 4 + ct;
          unsigned long v = 0;
#pragma unroll
          for (int j = 0; j < 8; ++j)
            v |= (unsigned long)SB[boffB + (ksr + j) * 128 + ((cB ^ j) << 4) + l15]
                 << (8 * j);
          bfr[ct] = v;
        }
#pragma unroll
        for (int rt = 0; rt < 4; ++rt)
#pragma unroll
          for (int ct = 0; ct < 4; ++ct)
            acc[rt][ct] = __builtin_amdgcn_mfma_f32_16x16x32_fp8_fp8(
                (long)af[rt], (long)bfr[ct], acc[rt][ct], 0, 0, 0);
      }
    }
    // store partial C-tile (owned exclusively by this block)
    float* Cp = Cpart + ((size_t)s * 28 + tile) * 16384;
#pragma unroll
    for (int rt = 0; rt < 4; ++rt)
#pragma unroll
      for (int ct = 0; ct < 4; ++ct)
#pragma unroll
        for (int r = 0; r < 4; ++r) {
          const int m = wy * 64 + rt * 16 + qd * 4 + r;  // C/D row map
          const int n = wx * 64 + ct * 16 + l15;         // C/D col map
          Cp[m * 128 + n] = acc[rt][ct][r];
        }
  } else {
    // ---- S-role: ln gram (bf16), 128x128 triangle tile + mask epilogue ----
    const int bb = b - 56;
    const int l = (bb & 7) * 66 + (bb >> 3);  // XCD swizzle (528 = 8*66)
    int bi = (int)((65.0f - sqrtf(4225.0f - 8.0f * (float)l)) * 0.5f);
    while (bi * (65 - bi) / 2 > l) --bi;
    while ((bi + 1) * (64 - bi) / 2 <= l) ++bi;
    const int bj = bi + (l - bi * (65 - bi) / 2);
    const int ti = bi * 128, tj = bj * 128;
    const bool offdiag = (bi != bj);
    const int boffB = offdiag ? 16384 : 0;

    const unsigned char* Pa = (const unsigned char*)(P + (size_t)ti * 128);
    const unsigned char* Pb = (const unsigned char*)(P + (size_t)tj * 128);
    for (int kc = 0; kc < 2; ++kc) {
      __syncthreads();
      STAGE_GEN(Pa + kc * 128, Pb + kc * 128, 256);
      __syncthreads();
      MFMA_B();
    }

    // ---- mask tiles -> LDS, reusing SB ----
    __syncthreads();
    unsigned char* MD = SB;          // [mrow][ncol], 16KB
    unsigned char* MM = SB + 16384;  // [ncol][mrow], 16KB
    const bool is_byte = ((const unsigned char*)mask)[4097] != 0;
    if (is_byte) {
      const unsigned char* m8d = (const unsigned char*)mask + (size_t)ti * 4096 + tj;
      const unsigned char* m8m = (const unsigned char*)mask + (size_t)tj * 4096 + ti;
#pragma unroll
      for (int it = 0; it < 4; ++it) {
        const int task = it * 256 + t;
        const int row = task >> 3, seg = task & 7;
        __builtin_amdgcn_global_load_lds(
            (const __attribute__((address_space(1))) void*)
                (m8d + (size_t)row * 4096 + seg * 16),
            (__attribute__((address_space(3))) void*)&MD[it * 4096 + wave * 1024],
            16, 0, 0);
        if (offdiag)
          __builtin_amdgcn_global_load_lds(
              (const __attribute__((address_space(1))) void*)
                  (m8m + (size_t)row * 4096 + seg * 16),
              (__attribute__((address_space(3))) void*)&MM[it * 4096 + wave * 1024],
              16, 0, 0);
      }
    } else {
      const unsigned int* m32 = (const unsigned int*)mask;
#pragma unroll
      for (int it = 0; it < 16; ++it) {
        const int task = it * 256 + t;
        const int row = task >> 5, seg = task & 31;
        uint4 v = *(const uint4*)&m32[(size_t)(ti + row) * 4096 + tj + seg * 4];
        uchar4 pk;
        pk.x = v.x ? 1 : 0; pk.y = v.y ? 1 : 0;
        pk.z = v.z ? 1 : 0; pk.w = v.w ? 1 : 0;
        *(uchar4*)&MD[row * 128 + seg * 4] = pk;
        if (offdiag) {
          uint4 w = *(const uint4*)&m32[(size_t)(tj + row) * 4096 + ti + seg * 4];
          uchar4 pm;
          pm.x = w.x ? 1 : 0; pm.y = w.y ? 1 : 0;
          pm.z = w.z ? 1 : 0; pm.w = w.w ? 1 : 0;
          *(uchar4*)&MM[row * 128 + seg * 4] = pm;
        }
      }
    }
    __syncthreads();

    float colp[4] = {0.f, 0.f, 0.f, 0.f};
#pragma unroll
    for (int rt = 0; rt < 4; ++rt) {
#pragma unroll
      for (int r = 0; r < 4; ++r) {
        const int mrow = wy * 64 + rt * 16 + qd * 4 + r;
        const int m = ti + mrow;
        float se = 0.f;
#pragma unroll
        for (int ct = 0; ct < 4; ++ct) {
          const int ncol = wx * 64 + ct * 16 + l15;
          const int n = tj + ncol;
          const float sim = acc[rt][ct][r] * 5.0f;         // /TEMPERATURE
          const float e = __expf(sim);
          if (offdiag || mrow != ncol) se += e;            // diag excluded
          if (offdiag) colp[ct] += e;
          if (MD[mrow * 128 + ncol]) {                     // sparse positives
            atomicAdd(&possum[m], sim);
            atomicAdd(&cntw[m], 1.0f);
          }
          if (offdiag && MM[ncol * 128 + mrow]) {          // mirror (n, m)
            atomicAdd(&possum[n], sim);
            atomicAdd(&cntw[n], 1.0f);
          }
        }
#pragma unroll
        for (int off = 1; off < 16; off <<= 1) se += __shfl_xor(se, off, 64);
        if (l15 == 0) redrow[mrow][wx] = se;
      }
    }
    if (offdiag) {
#pragma unroll
      for (int ct = 0; ct < 4; ++ct) {
        float ce = colp[ct];
        ce += __shfl_xor(ce, 16, 64);
        ce += __shfl_xor(ce, 32, 64);
        if (qd == 0) redcol[wx * 64 + ct * 16 + l15][wy] = ce;
      }
    }
    __syncthreads();
    if (t < 128) {
      atomicAdd(&rowexp[ti + t], redrow[t][0] + redrow[t][1]);
      if (offdiag) atomicAdd(&rowexp[tj + t], redcol[t][0] + redcol[t][1]);
    }
  }
}

// ---- gsq: combine split-K halves, sign-weighted Frobenius -> dtot ----
__global__ __launch_bounds__(256) void gsq(const float* __restrict__ Cpart,
                                           float* __restrict__ dtot) {
  const int tile = blockIdx.x;
  int I = 0, rem = tile;
  while (rem >= 7 - I) { rem -= 7 - I; ++I; }
  const int J = I + rem;
  const float mult = (I == J ? 1.f : 2.f) * (((I == 0) == (J == 0)) ? 1.f : -1.f);
  const float* a = Cpart + (size_t)tile * 16384;
  const float* bpt = Cpart + (size_t)(28 + tile) * 16384;
  const int t = threadIdx.x;
  float ssum = 0.f;
  for (int i = t; i < 16384; i += 256) {
    const float c = a[i] + bpt[i];
    ssum += c * c;
  }
#pragma unroll
  for (int off = 1; off < 64; off <<= 1) ssum += __shfl_xor(ssum, off, 64);
  __shared__ float sred[4];
  if ((t & 63) == 0) sred[t >> 6] = ssum;
  __syncthreads();
  if (t == 0) atomicAdd(dtot, mult * (sred[0] + sred[1] + sred[2] + sred[3]));
}

__global__ __launch_bounds__(1024) void finalize(const float* __restrict__ rowexp,
                                                 const float* __restrict__ possum,
                                                 const float* __restrict__ cnt,
                                                 const float* __restrict__ qpart,
                                                 const float* __restrict__ dtot,
                                                 float* __restrict__ out) {
  const int t = threadIdx.x;
  const int wave = t >> 6, lane = t & 63;
  float c = 0.f, q = 0.f;
  for (int m = t; m < 4096; m += 1024) {
    c += logf(rowexp[m]) - possum[m] / fmaxf(cnt[m], 1.0f);
    q += qpart[m];
  }
#pragma unroll
  for (int off = 1; off < 64; off <<= 1) {
    c += __shfl_xor(c, off, 64);
    q += __shfl_xor(q, off, 64);
  }
  __shared__ float sc[16], sq[16];
  if (lane == 0) { sc[wave] = c; sq[wave] = q; }
  __syncthreads();
  if (t == 0) {
    float C = 0.f, Q = 0.f;
    for (int i = 0; i < 16; ++i) { C += sc[i]; Q += sq[i]; }
    // dtot = 16384 * B^2 * loss_distill -> 0.5 * dtot / (4096^2 * 16384)
    out[0] = C * (1.0f / 4096.0f) + 0.5f * (dtot[0] * 3.6379788e-12f) +
             0.01f * (Q * (1.0f / 524288.0f));
  }
}

extern "C" void kernel_launch(void* const* d_in, const int* in_sizes, int n_in,
                              void* d_out, int out_size, void* d_ws, size_t ws_size,
                              hipStream_t stream) {
  const float* logits = (const float*)d_in[0];
  const float* hash = (const float*)d_in[1];
  const float* teacher = (const float*)d_in[2];
  const void* mask = d_in[3];
  float* out = (float*)d_out;

  char* ws = (char*)d_ws;
  float* rowexp = (float*)(ws + 0);
  float* possum = (float*)(ws + 16384);
  float* cntw = (float*)(ws + 32768);
  float* qpart = (float*)(ws + 49152);
  float* dtot = (float*)(ws + 65536);
  unsigned short* P = (unsigned short*)(ws + 98304);          // 4096x128 bf16 = 1 MB
  unsigned char* Q = (unsigned char*)(ws + 98304 + 1048576);  // 4096x896 fp8 = 3.5 MB
  float* Cpart = (float*)(ws + 4816896);  // 2 x 28 x 128x128 f32 = 3.5 MB

  prep<<<1024, 256, 0, stream>>>(logits, hash, teacher, P, Q, qpart, rowexp,
                                 possum, cntw, dtot);
  mega<<<584, 256, 0, stream>>>(P, Q, mask, rowexp, possum, cntw, Cpart);
  gsq<<<28, 256, 0, stream>>>(Cpart, dtot);
  finalize<<<1, 1024, 0, stream>>>(rowexp, possum, cntw, qpart, dtot, out);
}